// Round 9
// baseline (936.331 us; speedup 1.0000x reference)
//
#include <hip/hip_runtime.h>

#define C_ 256
#define HW_ 65536
#define IMG_ (C_*HW_)

typedef __attribute__((ext_vector_type(4))) float f32x4;
typedef __attribute__((ext_vector_type(8))) short s16x8;
typedef unsigned long long ull;

__device__ __forceinline__ ushort f2bf(float f) {
  union { float f; unsigned u; } v; v.f = f;
  unsigned u = v.u;
  return (ushort)((u + 0x7fffu + ((u >> 16) & 1u)) >> 16);
}

__device__ __forceinline__ s16x8 ldfrag(const ushort* p) {
  s16x8 v;
  ((ull*)&v)[0] = *(const ull*)(p);
  ((ull*)&v)[1] = *(const ull*)(p + 4);
  return v;
}

__device__ __forceinline__ void st8(ushort* d, uint4 u) {
  *(ull*)(d)     = ((ull*)&u)[0];
  *(ull*)(d + 4) = ((ull*)&u)[1];
}

// ---------------- per-plane stats ----------------
__global__ void k_stats1(const float* __restrict__ x, float2* __restrict__ part) {
  int bid = blockIdx.x;                  // 1024 = (b,c) planes
  int tid = threadIdx.x;
  const f32x4* p = (const f32x4*)(x + (size_t)bid*65536);
  float s = 0.f, ss = 0.f;
  #pragma unroll 4
  for (int i = tid; i < 16384; i += 256) {
    f32x4 v = p[i];
    s  += v[0]+v[1]+v[2]+v[3];
    ss += v[0]*v[0]+v[1]*v[1]+v[2]*v[2]+v[3]*v[3];
  }
  __shared__ float sa[256], sb[256];
  sa[tid]=s; sb[tid]=ss; __syncthreads();
  for (int k=128;k>0;k>>=1){
    if (tid<k){ sa[tid]+=sa[tid+k]; sb[tid]+=sb[tid+k]; }
    __syncthreads();
  }
  if (tid==0) part[bid] = make_float2(sa[0], sb[0]);
}

// ---------------- reduce to per-(b,group) mean/rstd ----------------
__global__ void k_stats2(const float2* __restrict__ part, float2* __restrict__ stats) {
  int i = threadIdx.x;              // 128 = b*32 + g
  int b = i >> 5, gg = i & 31;
  float s = 0.f, ss = 0.f;
  for (int j = 0; j < 8; ++j) { float2 v = part[b*256 + gg*8 + j]; s += v.x; ss += v.y; }
  float mean = s * (1.f/524288.f);
  float var  = ss * (1.f/524288.f) - mean*mean;
  stats[i] = make_float2(mean, rsqrtf(var + 1e-6f));
}

// ---------------- fold gamma (+scale) into bf16 weights; beta into bias ----------------
// m=0..2: Q/K/V (W' = W*gamma*s, b' = (b + W·beta)*s); m=3: wo plain
__global__ void k_fold(const float* __restrict__ wq, const float* __restrict__ bq,
                       const float* __restrict__ wk, const float* __restrict__ bk,
                       const float* __restrict__ wv, const float* __restrict__ bv,
                       const float* __restrict__ wo, const float* __restrict__ bo,
                       const float* __restrict__ gamma, const float* __restrict__ beta,
                       ushort* __restrict__ wAll, ushort* __restrict__ woE,
                       float* __restrict__ biasAll) {
  int m = blockIdx.x, o = threadIdx.x;
  const float* W  = m==0?wq : m==1?wk : m==2?wv : wo;
  const float* bi = m==0?bq : m==1?bk : m==2?bv : bo;
  ushort* dst = (m < 3) ? wAll + (size_t)m*65536 + (size_t)o*256 : woE + (size_t)o*256;
  float s = (m==0) ? 0.0625f : 1.0f;
  float acc = 0.f;
  for (int c4 = 0; c4 < 64; ++c4) {
    ushort4 pk;
    float w0 = W[o*256 + c4*4 + 0], w1 = W[o*256 + c4*4 + 1];
    float w2 = W[o*256 + c4*4 + 2], w3 = W[o*256 + c4*4 + 3];
    if (m < 3) {
      acc += w0*beta[c4*4+0] + w1*beta[c4*4+1] + w2*beta[c4*4+2] + w3*beta[c4*4+3];
      pk.x = f2bf(w0*gamma[c4*4+0]*s); pk.y = f2bf(w1*gamma[c4*4+1]*s);
      pk.z = f2bf(w2*gamma[c4*4+2]*s); pk.w = f2bf(w3*gamma[c4*4+3]*s);
    } else {
      pk.x = f2bf(w0); pk.y = f2bf(w1); pk.z = f2bf(w2); pk.w = f2bf(w3);
    }
    *(ushort4*)&dst[c4*4] = pk;
  }
  biasAll[m*256 + o] = (bi[o] + acc) * s;
}

// ---------------- fused GN + QKV projection: 128x128 blocks, 64x64/wave ----------------
// mat 0/1 -> Qt/Kt[win][t][c]; mat 2 -> V[win][c][t]. 12 blocks/window, XCD-chunked.
__global__ __launch_bounds__(256, 3) void k_proj(const float* __restrict__ x,
    const float2* __restrict__ stats, const ushort* __restrict__ wAll,
    const float* __restrict__ biasAll,
    ushort* __restrict__ Qt, ushort* __restrict__ Kt, ushort* __restrict__ V) {
  int g = blockIdx.x;
  int xcd = g & 7, i = g >> 3;
  int wq_ = i / 12; int win = xcd*128 + wq_; int r = i - wq_*12;
  int mat = r >> 2, q = r & 3;
  int t0 = (q >> 1)*128, c0 = (q & 1)*128;
  int b = win >> 8, wy = (win >> 4) & 15, wx = win & 15;
  int tid = threadIdx.x, l = tid & 63, wid = tid >> 6, h = l >> 4, lr = l & 15;
  int wr = wid >> 1, wc = wid & 1;

  // dbuf: buffer k at k*9216 (ushort units): X[128t][36] @+0, W[128co][36] @+4608
  __shared__ __align__(16) ushort smem[18432];

  const float* xw = x + (size_t)b*IMG_ + (size_t)wy*16*256 + wx*16;
  const ushort* wsrc = wAll + (size_t)mat*65536 + (size_t)c0*256;

  // X staging: thread = (tq 0..7)*32 + (cl 0..31); handles window-row tq of its t-half,
  // channel cb+cl; loads 16 contiguous f32 (one 64B px-row), writes 16 bf16 transposed.
  int cl = tid & 31, tq = tid >> 5;
  const float* xg0 = xw + (size_t)cl*HW_ + (size_t)((t0 >> 4) + tq)*256;

  // W staging: 2 threads/row, 32B each
  int srow = tid >> 1, shh = (tid & 1)*16;
  const ushort* wg = wsrc + (size_t)srow*256 + shh;

  f32x4 acc[4][4];
  #pragma unroll
  for (int a = 0; a < 4; ++a)
    #pragma unroll
    for (int n = 0; n < 4; ++n) acc[a][n] = (f32x4){0.f,0.f,0.f,0.f};

  int aoff = (mat < 2) ? 0 : 4608;     // A rows: t (X) for Q/K, co (W) for V
  int boff = (mat < 2) ? 4608 : 0;

  f32x4 xa0, xa1, xa2, xa3;
  uint4 rw0, rw1;
  // prologue: load ck=0
  xa0 = *(const f32x4*)(xg0);      xa1 = *(const f32x4*)(xg0 + 4);
  xa2 = *(const f32x4*)(xg0 + 8);  xa3 = *(const f32x4*)(xg0 + 12);
  rw0 = *(const uint4*)(wg);       rw1 = *(const uint4*)(wg + 8);
  {
    float2 st = stats[b*32 + (cl >> 3)];
    ushort* xd = smem + (size_t)(tq*16)*36 + cl;
    #pragma unroll
    for (int k = 0; k < 4; ++k) xd[k*36]        = f2bf((xa0[k]-st.x)*st.y);
    #pragma unroll
    for (int k = 0; k < 4; ++k) xd[(k+4)*36]    = f2bf((xa1[k]-st.x)*st.y);
    #pragma unroll
    for (int k = 0; k < 4; ++k) xd[(k+8)*36]    = f2bf((xa2[k]-st.x)*st.y);
    #pragma unroll
    for (int k = 0; k < 4; ++k) xd[(k+12)*36]   = f2bf((xa3[k]-st.x)*st.y);
    ushort* wd = smem + 4608 + srow*36 + shh;
    st8(wd, rw0); st8(wd + 8, rw1);
  }
  __syncthreads();

  int cur = 0;
  for (int ck = 0; ck < 8; ++ck) {
    if (ck < 7) {
      const float* xp = xg0 + (size_t)(ck + 1)*32*HW_;
      xa0 = *(const f32x4*)(xp);      xa1 = *(const f32x4*)(xp + 4);
      xa2 = *(const f32x4*)(xp + 8);  xa3 = *(const f32x4*)(xp + 12);
      const ushort* wp = wg + (ck + 1)*32;
      rw0 = *(const uint4*)(wp);      rw1 = *(const uint4*)(wp + 8);
    }
    const ushort* ab = smem + cur*9216 + aoff;
    const ushort* bb = smem + cur*9216 + boff;
    s16x8 af[4], bf[4];
    #pragma unroll
    for (int ms = 0; ms < 4; ++ms)
      af[ms] = ldfrag(ab + (size_t)(wr*64 + ms*16 + lr)*36 + h*8);
    #pragma unroll
    for (int ns = 0; ns < 4; ++ns)
      bf[ns] = ldfrag(bb + (size_t)(wc*64 + ns*16 + lr)*36 + h*8);
    #pragma unroll
    for (int ms = 0; ms < 4; ++ms)
      #pragma unroll
      for (int ns = 0; ns < 4; ++ns)
        acc[ms][ns] = __builtin_amdgcn_mfma_f32_16x16x32_bf16(af[ms], bf[ns], acc[ms][ns], 0,0,0);
    if (ck < 7) {
      float2 st = stats[b*32 + (ck + 1)*4 + (cl >> 3)];
      ushort* xd = smem + (cur^1)*9216 + (size_t)(tq*16)*36 + cl;
      #pragma unroll
      for (int k = 0; k < 4; ++k) xd[k*36]      = f2bf((xa0[k]-st.x)*st.y);
      #pragma unroll
      for (int k = 0; k < 4; ++k) xd[(k+4)*36]  = f2bf((xa1[k]-st.x)*st.y);
      #pragma unroll
      for (int k = 0; k < 4; ++k) xd[(k+8)*36]  = f2bf((xa2[k]-st.x)*st.y);
      #pragma unroll
      for (int k = 0; k < 4; ++k) xd[(k+12)*36] = f2bf((xa3[k]-st.x)*st.y);
      ushort* wd = smem + (cur^1)*9216 + 4608 + srow*36 + shh;
      st8(wd, rw0); st8(wd + 8, rw1);
    }
    __syncthreads();
    cur ^= 1;
  }

  // ---- epilogue: 2 slab passes [128][68] over B-dim 64-halves; wide 16B stores ----
  ushort* dst = (mat == 0) ? Qt + (size_t)win*65536
              : (mat == 1) ? Kt + (size_t)win*65536
                           : V  + (size_t)win*65536;
  int row0 = (mat < 2) ? t0 : c0;
  int col0 = (mat < 2) ? c0 : t0;

  float bc[4]; f32x4 br[4];
  if (mat < 2) {
    #pragma unroll
    for (int ns = 0; ns < 4; ++ns)
      bc[ns] = biasAll[mat*256 + c0 + wc*64 + ns*16 + lr];
  } else {
    #pragma unroll
    for (int ms = 0; ms < 4; ++ms)
      br[ms] = *(const f32x4*)&biasAll[2*256 + c0 + wr*64 + ms*16 + 4*h];
  }

  #pragma unroll
  for (int sl = 0; sl < 2; ++sl) {
    if (wc == sl) {
      #pragma unroll
      for (int ms = 0; ms < 4; ++ms)
        #pragma unroll
        for (int ns = 0; ns < 4; ++ns)
          #pragma unroll
          for (int j = 0; j < 4; ++j) {
            int row = wr*64 + ms*16 + 4*h + j;
            float v = acc[ms][ns][j] + ((mat < 2) ? bc[ns] : br[ms][j]);
            smem[row*68 + ns*16 + lr] = f2bf(v);
          }
    }
    __syncthreads();
    #pragma unroll
    for (int p = 0; p < 4; ++p) {
      int rr = p*32 + (tid >> 3), seg = tid & 7;
      const ushort* sp = &smem[rr*68 + seg*8];
      uint4 v;
      ((ull*)&v)[0] = *(const ull*)sp;
      ((ull*)&v)[1] = *(const ull*)(sp + 4);
      *(uint4*)(dst + (size_t)(row0 + rr)*256 + col0 + sl*64 + seg*8) = v;
    }
    if (sl == 0) __syncthreads();
  }
}

// ---------------- windowed attention: q-split waves, Q-in-regs, 64-key tiles ----------------
__global__ __launch_bounds__(256, 2) void k_attn(const ushort* __restrict__ Qt,
    const ushort* __restrict__ Kt, const ushort* __restrict__ V,
    ushort* __restrict__ AO) {
  int g = blockIdx.x;
  int i = g >> 3;
  int w = (g & 7)*128 + (i >> 2), qt = i & 3;
  int q0 = qt * 64;
  int tid = threadIdx.x, l = tid & 63, wid = tid >> 6, h = l >> 4, lr = l & 15;
  __shared__ __align__(16) ushort KV[17408];
  __shared__ __align__(16) ushort Ps[4][1088];   // per-wave P-subtile [16 q][68]
  const ushort* qbase = Qt + (size_t)w*65536;
  const ushort* kbase = Kt + (size_t)w*65536;
  const ushort* vbase = V  + (size_t)w*65536;

  s16x8 qf[8];
  {
    const ushort* qp = qbase + (size_t)(q0 + wid*16 + lr)*256 + h*8;
    #pragma unroll
    for (int dk = 0; dk < 8; ++dk) {
      uint4 u = *(const uint4*)(qp + dk*32);
      qf[dk] = *(s16x8*)&u;
    }
  }

  int krow = tid >> 2, kseg = (tid & 3)*64;
  const ushort* kg = kbase + (size_t)krow*256 + kseg;
  ushort* kd = &KV[krow*260 + kseg];
  const ushort* vg = vbase + (size_t)tid*256;
  ushort* vd = &KV[tid*68];

  uint4 rv[8];
  #pragma unroll
  for (int u = 0; u < 8; ++u) rv[u] = *(const uint4*)(kg + u*8);
  #pragma unroll
  for (int u = 0; u < 8; ++u) st8(kd + u*8, rv[u]);
  __syncthreads();

  f32x4 accS[16];
  #pragma unroll
  for (int n = 0; n < 16; ++n) accS[n] = (f32x4){0.f,0.f,0.f,0.f};

  #pragma unroll
  for (int kt = 0; kt < 4; ++kt) {
    if (kt < 3) {
      const ushort* kp = kg + (size_t)(kt + 1)*64*256;
      #pragma unroll
      for (int u = 0; u < 8; ++u) rv[u] = *(const uint4*)(kp + u*8);
    } else {
      #pragma unroll
      for (int u = 0; u < 8; ++u) rv[u] = *(const uint4*)(vg + u*8);
    }
    #pragma unroll
    for (int ns = 0; ns < 4; ++ns) {
      #pragma unroll
      for (int dstep = 0; dstep < 8; ++dstep) {
        s16x8 kf = ldfrag(&KV[(ns*16 + lr)*260 + dstep*32 + h*8]);
        accS[kt*4 + ns] = __builtin_amdgcn_mfma_f32_16x16x32_bf16(qf[dstep], kf, accS[kt*4 + ns], 0,0,0);
      }
    }
    __syncthreads();
    if (kt < 3) {
      #pragma unroll
      for (int u = 0; u < 8; ++u) st8(kd + u*8, rv[u]);
    } else {
      #pragma unroll
      for (int u = 0; u < 8; ++u) st8(vd + u*8, rv[u]);
    }
    __syncthreads();
  }

  #pragma unroll
  for (int j = 0; j < 4; ++j) {
    float m_ = accS[0][j];
    #pragma unroll
    for (int n = 1; n < 16; ++n) m_ = fmaxf(m_, accS[n][j]);
    #pragma unroll
    for (int msk = 1; msk < 16; msk <<= 1) m_ = fmaxf(m_, __shfl_xor(m_, msk));
    float s_ = 0.f;
    #pragma unroll
    for (int n = 0; n < 16; ++n) {
      float p = __expf(accS[n][j] - m_);
      accS[n][j] = p;
      s_ += p;
    }
    #pragma unroll
    for (int msk = 1; msk < 16; msk <<= 1) s_ += __shfl_xor(s_, msk);
    float ri = 1.f / s_;
    #pragma unroll
    for (int n = 0; n < 16; ++n) accS[n][j] *= ri;
  }

  // PV: Ps write -> __syncthreads() -> ldfrag is REQUIRED (round-6 NaN lesson)
  f32x4 accO[16];
  #pragma unroll
  for (int n = 0; n < 16; ++n) accO[n] = (f32x4){0.f,0.f,0.f,0.f};

  #pragma unroll
  for (int kt = 0; kt < 4; ++kt) {
    if (kt < 3) {
      const ushort* vp = vg + (kt + 1)*64;
      #pragma unroll
      for (int u = 0; u < 8; ++u) rv[u] = *(const uint4*)(vp + u*8);
    }
    #pragma unroll
    for (int ns = 0; ns < 4; ++ns)
      #pragma unroll
      for (int j = 0; j < 4; ++j)
        Ps[wid][(4*h + j)*68 + ns*16 + lr] = f2bf(accS[kt*4 + ns][j]);
    __syncthreads();
    #pragma unroll
    for (int ks = 0; ks < 2; ++ks) {
      s16x8 pf = ldfrag(&Ps[wid][lr*68 + ks*32 + h*8]);
      #pragma unroll
      for (int ns = 0; ns < 16; ++ns) {
        s16x8 vf = ldfrag(&KV[(ns*16 + lr)*68 + ks*32 + h*8]);
        accO[ns] = __builtin_amdgcn_mfma_f32_16x16x32_bf16(pf, vf, accO[ns], 0,0,0);
      }
    }
    __syncthreads();
    if (kt < 3) {
      #pragma unroll
      for (int u = 0; u < 8; ++u) st8(vd + u*8, rv[u]);
      __syncthreads();
    }
  }

  #pragma unroll
  for (int ns = 0; ns < 16; ++ns)
    #pragma unroll
    for (int j = 0; j < 4; ++j)
      KV[(wid*16 + 4*h + j)*260 + ns*16 + lr] = f2bf(accO[ns][j]);
  __syncthreads();
  ushort* aob = AO + (size_t)w*65536;
  #pragma unroll
  for (int it = 0; it < 8; ++it) {
    int task = tid + 256*it;
    int r = task >> 5, seg = task & 31;
    const ushort* sp = &KV[r*260 + seg*8];
    uint4 v;
    ((ull*)&v)[0] = *(const ull*)sp;
    ((ull*)&v)[1] = *(const ull*)(sp + 4);
    *(uint4*)(aob + (size_t)(q0 + r)*256 + seg*8) = v;
  }
}

// ---------------- output projection + residual: 128x128 blocks, 64x64/wave ----------------
__global__ __launch_bounds__(256, 3) void k_oproj(const float* __restrict__ x,
    const ushort* __restrict__ AO, const ushort* __restrict__ woE,
    const float* __restrict__ biasAll, float* __restrict__ y) {
  int g = blockIdx.x;
  int i = g >> 3;
  int w = (g & 7)*128 + (i >> 2);
  int q = i & 3;
  int o0 = (q >> 1)*128, t0 = (q & 1)*128;
  int b = w >> 8, wy = (w >> 4) & 15, wx = w & 15;
  int tid = threadIdx.x, l = tid & 63, wid = tid >> 6, h = l >> 4, lr = l & 15;
  int wr = wid >> 1, wc = wid & 1;

  __shared__ __align__(16) ushort smem[18432];

  const ushort* abase = AO + (size_t)w*65536 + (size_t)t0*256;
  const ushort* wbase = woE + (size_t)o0*256;

  int srow = tid >> 1, shh = (tid & 1)*16;
  const ushort* ag = abase + (size_t)srow*256 + shh;
  const ushort* wg = wbase + (size_t)srow*256 + shh;

  f32x4 acc[4][4];
  #pragma unroll
  for (int a = 0; a < 4; ++a)
    #pragma unroll
    for (int n = 0; n < 4; ++n) acc[a][n] = (f32x4){0.f,0.f,0.f,0.f};

  uint4 rw0, rw1, ra0, ra1;
  rw0 = *(const uint4*)(wg);     rw1 = *(const uint4*)(wg + 8);
  ra0 = *(const uint4*)(ag);     ra1 = *(const uint4*)(ag + 8);
  {
    ushort* wd = smem + srow*36 + shh;
    st8(wd, rw0); st8(wd + 8, rw1);
    ushort* ad = smem + 4608 + srow*36 + shh;
    st8(ad, ra0); st8(ad + 8, ra1);
  }
  __syncthreads();

  int cur = 0;
  for (int ck = 0; ck < 8; ++ck) {
    if (ck < 7) {
      const ushort* wp = wg + (ck + 1)*32;
      const ushort* ap = ag + (ck + 1)*32;
      rw0 = *(const uint4*)(wp);   rw1 = *(const uint4*)(wp + 8);
      ra0 = *(const uint4*)(ap);   ra1 = *(const uint4*)(ap + 8);
    }
    const ushort* wb = smem + cur*9216;
    const ushort* ab = smem + cur*9216 + 4608;
    s16x8 af[4], bf[4];
    #pragma unroll
    for (int ms = 0; ms < 4; ++ms)
      af[ms] = ldfrag(wb + (size_t)(wr*64 + ms*16 + lr)*36 + h*8);
    #pragma unroll
    for (int ns = 0; ns < 4; ++ns)
      bf[ns] = ldfrag(ab + (size_t)(wc*64 + ns*16 + lr)*36 + h*8);
    #pragma unroll
    for (int ms = 0; ms < 4; ++ms)
      #pragma unroll
      for (int ns = 0; ns < 4; ++ns)
        acc[ms][ns] = __builtin_amdgcn_mfma_f32_16x16x32_bf16(af[ms], bf[ns], acc[ms][ns], 0,0,0);
    if (ck < 7) {
      ushort* wd = smem + (cur^1)*9216 + srow*36 + shh;
      st8(wd, rw0); st8(wd + 8, rw1);
      ushort* ad = smem + (cur^1)*9216 + 4608 + srow*36 + shh;
      st8(ad, ra0); st8(ad + 8, ra1);
    }
    __syncthreads();
    cur ^= 1;
  }

  const float* xw = x + (size_t)b*IMG_ + wy*16*256 + wx*16;
  float* yw = y + (size_t)b*IMG_ + wy*16*256 + wx*16;
  #pragma unroll
  for (int ms = 0; ms < 4; ++ms) {
    f32x4 b4 = *(const f32x4*)&biasAll[768 + o0 + wr*64 + ms*16 + 4*h];
    #pragma unroll
    for (int j = 0; j < 4; ++j) {
      int o = o0 + wr*64 + ms*16 + 4*h + j;
      #pragma unroll
      for (int ns = 0; ns < 4; ++ns) {
        int t = t0 + wc*64 + ns*16 + lr;
        size_t off = (size_t)o*HW_ + (t >> 4)*256 + (t & 15);
        yw[off] = xw[off] + acc[ms][ns][j] + b4[j];
      }
    }
  }
}

extern "C" void kernel_launch(void* const* d_in, const int* in_sizes, int n_in,
                              void* d_out, int out_size, void* d_ws, size_t ws_size,
                              hipStream_t stream) {
  const float* x     = (const float*)d_in[0];
  const float* gamma = (const float*)d_in[1];
  const float* beta  = (const float*)d_in[2];
  const float* wq = (const float*)d_in[3];
  const float* bq = (const float*)d_in[4];
  const float* wk = (const float*)d_in[5];
  const float* bk = (const float*)d_in[6];
  const float* wv = (const float*)d_in[7];
  const float* bv = (const float*)d_in[8];
  const float* wo = (const float*)d_in[9];
  const float* bo = (const float*)d_in[10];
  float* y = (float*)d_out;
  char* ws = (char*)d_ws;

  float2* part    = (float2*)ws;                        // 8 KB
  float*  biasAll = (float*)(ws + 8192);                // 4 KB
  float2* stats   = (float2*)(ws + 16384);              // 1 KB
  ushort* wAll    = (ushort*)(ws + 32768);              // 384 KB
  ushort* woE     = (ushort*)(ws + 32768 + 393216);     // 128 KB
  ushort* Qt      = (ushort*)(ws + 2097152);            // 134 MB (also AO)
  // d_out holds Kt @0 and V @+134MB until k_oproj overwrites all of it with y.
  ushort* Kt = (ushort*)d_out;
  ushort* V  = (ushort*)d_out + (size_t)67108864;

  k_stats1<<<1024, 256, 0, stream>>>(x, part);
  k_stats2<<<1, 128, 0, stream>>>(part, stats);
  k_fold<<<4, 256, 0, stream>>>(wq,bq,wk,bk,wv,bv,wo,bo,gamma,beta,wAll,woE,biasAll);
  k_proj<<<12288, 256, 0, stream>>>(x, stats, wAll, biasAll, Qt, Kt, V);
  k_attn<<<4096, 256, 0, stream>>>(Qt, Kt, V, Qt /*AO alias: disjoint rows*/);
  k_oproj<<<4096, 256, 0, stream>>>(x, Qt /*AO*/, woE, biasAll, y);
}

// Round 10
// 925.807 us; speedup vs baseline: 1.0114x; 1.0114x over previous
//
#include <hip/hip_runtime.h>

#define C_ 256
#define HW_ 65536
#define IMG_ (C_*HW_)

typedef __attribute__((ext_vector_type(4))) float f32x4;
typedef __attribute__((ext_vector_type(8))) short s16x8;
typedef unsigned long long ull;

__device__ __forceinline__ ushort f2bf(float f) {
  union { float f; unsigned u; } v; v.f = f;
  unsigned u = v.u;
  return (ushort)((u + 0x7fffu + ((u >> 16) & 1u)) >> 16);
}

// packed f32x2 -> bf16x2 (RNE), gfx950 HW op; no builtin exists (T12 recipe)
__device__ __forceinline__ unsigned cvtpk(float lo, float hi) {
  unsigned r;
  asm("v_cvt_pk_bf16_f32 %0, %1, %2" : "=v"(r) : "v"(lo), "v"(hi));
  return r;
}

__device__ __forceinline__ s16x8 ldfrag(const ushort* p) {
  s16x8 v;
  ((ull*)&v)[0] = *(const ull*)(p);
  ((ull*)&v)[1] = *(const ull*)(p + 4);
  return v;
}

__device__ __forceinline__ void st8(ushort* d, uint4 u) {
  *(ull*)(d)     = ((ull*)&u)[0];
  *(ull*)(d + 4) = ((ull*)&u)[1];
}

// ---------------- per-plane stats ----------------
__global__ void k_stats1(const float* __restrict__ x, float2* __restrict__ part) {
  int bid = blockIdx.x;                  // 1024 = (b,c) planes
  int tid = threadIdx.x;
  const f32x4* p = (const f32x4*)(x + (size_t)bid*65536);
  float s = 0.f, ss = 0.f;
  #pragma unroll 4
  for (int i = tid; i < 16384; i += 256) {
    f32x4 v = p[i];
    s  += v[0]+v[1]+v[2]+v[3];
    ss += v[0]*v[0]+v[1]*v[1]+v[2]*v[2]+v[3]*v[3];
  }
  __shared__ float sa[256], sb[256];
  sa[tid]=s; sb[tid]=ss; __syncthreads();
  for (int k=128;k>0;k>>=1){
    if (tid<k){ sa[tid]+=sa[tid+k]; sb[tid]+=sb[tid+k]; }
    __syncthreads();
  }
  if (tid==0) part[bid] = make_float2(sa[0], sb[0]);
}

// ---------------- reduce to per-(b,group) mean/rstd ----------------
__global__ void k_stats2(const float2* __restrict__ part, float2* __restrict__ stats) {
  int i = threadIdx.x;              // 128 = b*32 + g
  int b = i >> 5, gg = i & 31;
  float s = 0.f, ss = 0.f;
  for (int j = 0; j < 8; ++j) { float2 v = part[b*256 + gg*8 + j]; s += v.x; ss += v.y; }
  float mean = s * (1.f/524288.f);
  float var  = ss * (1.f/524288.f) - mean*mean;
  stats[i] = make_float2(mean, rsqrtf(var + 1e-6f));
}

// ---------------- fold gamma (+scale) into bf16 weights; beta into bias ----------------
// m=0..2: Q/K/V (W' = W*gamma*s, b' = (b + W·beta)*s); m=3: wo plain
__global__ void k_fold(const float* __restrict__ wq, const float* __restrict__ bq,
                       const float* __restrict__ wk, const float* __restrict__ bk,
                       const float* __restrict__ wv, const float* __restrict__ bv,
                       const float* __restrict__ wo, const float* __restrict__ bo,
                       const float* __restrict__ gamma, const float* __restrict__ beta,
                       ushort* __restrict__ wAll, ushort* __restrict__ woE,
                       float* __restrict__ biasAll) {
  int m = blockIdx.x, o = threadIdx.x;
  const float* W  = m==0?wq : m==1?wk : m==2?wv : wo;
  const float* bi = m==0?bq : m==1?bk : m==2?bv : bo;
  ushort* dst = (m < 3) ? wAll + (size_t)m*65536 + (size_t)o*256 : woE + (size_t)o*256;
  float s = (m==0) ? 0.0625f : 1.0f;
  float acc = 0.f;
  for (int c4 = 0; c4 < 64; ++c4) {
    ushort4 pk;
    float w0 = W[o*256 + c4*4 + 0], w1 = W[o*256 + c4*4 + 1];
    float w2 = W[o*256 + c4*4 + 2], w3 = W[o*256 + c4*4 + 3];
    if (m < 3) {
      acc += w0*beta[c4*4+0] + w1*beta[c4*4+1] + w2*beta[c4*4+2] + w3*beta[c4*4+3];
      pk.x = f2bf(w0*gamma[c4*4+0]*s); pk.y = f2bf(w1*gamma[c4*4+1]*s);
      pk.z = f2bf(w2*gamma[c4*4+2]*s); pk.w = f2bf(w3*gamma[c4*4+3]*s);
    } else {
      pk.x = f2bf(w0); pk.y = f2bf(w1); pk.z = f2bf(w2); pk.w = f2bf(w3);
    }
    *(ushort4*)&dst[c4*4] = pk;
  }
  biasAll[m*256 + o] = (bi[o] + acc) * s;
}

// ---------------- fused GN + QKV projection: 128x128 blocks, 64x64/wave ----------------
// mat 0/1 -> Qt/Kt[win][t][c]; mat 2 -> V[win][c][t]. 12 blocks/window, XCD-chunked.
// Staging: thread = (t8 0..15)*16 + cpr 0..15 -> 2 channels (2*cpr, 2*cpr+1) x 8 t;
// GN via fmaf, pack via v_cvt_pk_bf16_f32, 8 dword LDS writes (2-way banks = free).
__global__ __launch_bounds__(256, 3) void k_proj(const float* __restrict__ x,
    const float2* __restrict__ stats, const ushort* __restrict__ wAll,
    const float* __restrict__ biasAll,
    ushort* __restrict__ Qt, ushort* __restrict__ Kt, ushort* __restrict__ V) {
  int g = blockIdx.x;
  int xcd = g & 7, i = g >> 3;
  int wq_ = i / 12; int win = xcd*128 + wq_; int r = i - wq_*12;
  int mat = r >> 2, q = r & 3;
  int t0 = (q >> 1)*128, c0 = (q & 1)*128;
  int b = win >> 8, wy = (win >> 4) & 15, wx = win & 15;
  int tid = threadIdx.x, l = tid & 63, wid = tid >> 6, h = l >> 4, lr = l & 15;
  int wr = wid >> 1, wc = wid & 1;

  // dbuf: buffer k at k*9216 (ushort units): X[128t][36] @+0, W[128co][36] @+4608
  __shared__ __align__(16) ushort smem[18432];

  const float* xw = x + (size_t)b*IMG_ + (size_t)wy*16*256 + wx*16;
  const ushort* wsrc = wAll + (size_t)mat*65536 + (size_t)c0*256;

  // X staging geometry
  int cpr = tid & 15, t8 = tid >> 4;
  int tl = t8*8;
  int rowoff = ((t0 >> 4) + (t8 >> 1))*256 + (t8 & 1)*8;   // 8 contiguous f32
  const float* xgA = xw + (size_t)(2*cpr)*HW_ + rowoff;
  const float* xgB = xgA + HW_;

  // W staging: 2 threads/row, 32B each
  int srow = tid >> 1, shh = (tid & 1)*16;
  const ushort* wg = wsrc + (size_t)srow*256 + shh;

  f32x4 acc[4][4];
  #pragma unroll
  for (int a = 0; a < 4; ++a)
    #pragma unroll
    for (int n = 0; n < 4; ++n) acc[a][n] = (f32x4){0.f,0.f,0.f,0.f};

  int aoff = (mat < 2) ? 0 : 4608;     // A rows: t (X) for Q/K, co (W) for V
  int boff = (mat < 2) ? 4608 : 0;

  f32x4 va0, va1, vb0, vb1;
  uint4 rw0, rw1;
  // prologue: load ck=0
  va0 = *(const f32x4*)(xgA);      va1 = *(const f32x4*)(xgA + 4);
  vb0 = *(const f32x4*)(xgB);      vb1 = *(const f32x4*)(xgB + 4);
  rw0 = *(const uint4*)(wg);       rw1 = *(const uint4*)(wg + 8);
  {
    float2 st = stats[b*32 + (cpr >> 2)];
    float sa = st.y, sb2 = -st.x*st.y;
    ushort* xd = smem + (size_t)tl*36 + 2*cpr;
    #pragma unroll
    for (int k = 0; k < 4; ++k) {
      *(unsigned*)&xd[k*36]     = cvtpk(fmaf(va0[k],sa,sb2), fmaf(vb0[k],sa,sb2));
      *(unsigned*)&xd[(k+4)*36] = cvtpk(fmaf(va1[k],sa,sb2), fmaf(vb1[k],sa,sb2));
    }
    ushort* wd = smem + 4608 + srow*36 + shh;
    st8(wd, rw0); st8(wd + 8, rw1);
  }
  __syncthreads();

  int cur = 0;
  for (int ck = 0; ck < 8; ++ck) {
    if (ck < 7) {
      size_t off = (size_t)(ck + 1)*32*HW_;
      va0 = *(const f32x4*)(xgA + off);      va1 = *(const f32x4*)(xgA + off + 4);
      vb0 = *(const f32x4*)(xgB + off);      vb1 = *(const f32x4*)(xgB + off + 4);
      const ushort* wp = wg + (ck + 1)*32;
      rw0 = *(const uint4*)(wp);      rw1 = *(const uint4*)(wp + 8);
    }
    const ushort* ab = smem + cur*9216 + aoff;
    const ushort* bb = smem + cur*9216 + boff;
    s16x8 af[4], bf[4];
    #pragma unroll
    for (int ms = 0; ms < 4; ++ms)
      af[ms] = ldfrag(ab + (size_t)(wr*64 + ms*16 + lr)*36 + h*8);
    #pragma unroll
    for (int ns = 0; ns < 4; ++ns)
      bf[ns] = ldfrag(bb + (size_t)(wc*64 + ns*16 + lr)*36 + h*8);
    #pragma unroll
    for (int ms = 0; ms < 4; ++ms)
      #pragma unroll
      for (int ns = 0; ns < 4; ++ns)
        acc[ms][ns] = __builtin_amdgcn_mfma_f32_16x16x32_bf16(af[ms], bf[ns], acc[ms][ns], 0,0,0);
    if (ck < 7) {
      float2 st = stats[b*32 + (ck + 1)*4 + (cpr >> 2)];
      float sa = st.y, sb2 = -st.x*st.y;
      ushort* xd = smem + (cur^1)*9216 + (size_t)tl*36 + 2*cpr;
      #pragma unroll
      for (int k = 0; k < 4; ++k) {
        *(unsigned*)&xd[k*36]     = cvtpk(fmaf(va0[k],sa,sb2), fmaf(vb0[k],sa,sb2));
        *(unsigned*)&xd[(k+4)*36] = cvtpk(fmaf(va1[k],sa,sb2), fmaf(vb1[k],sa,sb2));
      }
      ushort* wd = smem + (cur^1)*9216 + 4608 + srow*36 + shh;
      st8(wd, rw0); st8(wd + 8, rw1);
    }
    __syncthreads();
    cur ^= 1;
  }

  // ---- epilogue: 2 slab passes [128][68] over B-dim 64-halves; wide 16B stores ----
  ushort* dst = (mat == 0) ? Qt + (size_t)win*65536
              : (mat == 1) ? Kt + (size_t)win*65536
                           : V  + (size_t)win*65536;
  int row0 = (mat < 2) ? t0 : c0;
  int col0 = (mat < 2) ? c0 : t0;

  float bc[4]; f32x4 br[4];
  if (mat < 2) {
    #pragma unroll
    for (int ns = 0; ns < 4; ++ns)
      bc[ns] = biasAll[mat*256 + c0 + wc*64 + ns*16 + lr];
  } else {
    #pragma unroll
    for (int ms = 0; ms < 4; ++ms)
      br[ms] = *(const f32x4*)&biasAll[2*256 + c0 + wr*64 + ms*16 + 4*h];
  }

  #pragma unroll
  for (int sl = 0; sl < 2; ++sl) {
    if (wc == sl) {
      #pragma unroll
      for (int ms = 0; ms < 4; ++ms)
        #pragma unroll
        for (int ns = 0; ns < 4; ++ns)
          #pragma unroll
          for (int j = 0; j < 4; ++j) {
            int row = wr*64 + ms*16 + 4*h + j;
            float v = acc[ms][ns][j] + ((mat < 2) ? bc[ns] : br[ms][j]);
            smem[row*68 + ns*16 + lr] = f2bf(v);
          }
    }
    __syncthreads();
    #pragma unroll
    for (int p = 0; p < 4; ++p) {
      int rr = p*32 + (tid >> 3), seg = tid & 7;
      const ushort* sp = &smem[rr*68 + seg*8];
      uint4 v;
      ((ull*)&v)[0] = *(const ull*)sp;
      ((ull*)&v)[1] = *(const ull*)(sp + 4);
      *(uint4*)(dst + (size_t)(row0 + rr)*256 + col0 + sl*64 + seg*8) = v;
    }
    if (sl == 0) __syncthreads();
  }
}

// ---------------- windowed attention: q-split waves, Q-in-regs, 64-key tiles ----------------
__global__ __launch_bounds__(256, 2) void k_attn(const ushort* __restrict__ Qt,
    const ushort* __restrict__ Kt, const ushort* __restrict__ V,
    ushort* __restrict__ AO) {
  int g = blockIdx.x;
  int i = g >> 3;
  int w = (g & 7)*128 + (i >> 2), qt = i & 3;
  int q0 = qt * 64;
  int tid = threadIdx.x, l = tid & 63, wid = tid >> 6, h = l >> 4, lr = l & 15;
  __shared__ __align__(16) ushort KV[17408];
  __shared__ __align__(16) ushort Ps[4][1088];   // per-wave P-subtile [16 q][68]
  const ushort* qbase = Qt + (size_t)w*65536;
  const ushort* kbase = Kt + (size_t)w*65536;
  const ushort* vbase = V  + (size_t)w*65536;

  s16x8 qf[8];
  {
    const ushort* qp = qbase + (size_t)(q0 + wid*16 + lr)*256 + h*8;
    #pragma unroll
    for (int dk = 0; dk < 8; ++dk) {
      uint4 u = *(const uint4*)(qp + dk*32);
      qf[dk] = *(s16x8*)&u;
    }
  }

  int krow = tid >> 2, kseg = (tid & 3)*64;
  const ushort* kg = kbase + (size_t)krow*256 + kseg;
  ushort* kd = &KV[krow*260 + kseg];
  const ushort* vg = vbase + (size_t)tid*256;
  ushort* vd = &KV[tid*68];

  uint4 rv[8];
  #pragma unroll
  for (int u = 0; u < 8; ++u) rv[u] = *(const uint4*)(kg + u*8);
  #pragma unroll
  for (int u = 0; u < 8; ++u) st8(kd + u*8, rv[u]);
  __syncthreads();

  f32x4 accS[16];
  #pragma unroll
  for (int n = 0; n < 16; ++n) accS[n] = (f32x4){0.f,0.f,0.f,0.f};

  #pragma unroll
  for (int kt = 0; kt < 4; ++kt) {
    if (kt < 3) {
      const ushort* kp = kg + (size_t)(kt + 1)*64*256;
      #pragma unroll
      for (int u = 0; u < 8; ++u) rv[u] = *(const uint4*)(kp + u*8);
    } else {
      #pragma unroll
      for (int u = 0; u < 8; ++u) rv[u] = *(const uint4*)(vg + u*8);
    }
    #pragma unroll
    for (int ns = 0; ns < 4; ++ns) {
      #pragma unroll
      for (int dstep = 0; dstep < 8; ++dstep) {
        s16x8 kf = ldfrag(&KV[(ns*16 + lr)*260 + dstep*32 + h*8]);
        accS[kt*4 + ns] = __builtin_amdgcn_mfma_f32_16x16x32_bf16(qf[dstep], kf, accS[kt*4 + ns], 0,0,0);
      }
    }
    __syncthreads();
    if (kt < 3) {
      #pragma unroll
      for (int u = 0; u < 8; ++u) st8(kd + u*8, rv[u]);
    } else {
      #pragma unroll
      for (int u = 0; u < 8; ++u) st8(vd + u*8, rv[u]);
    }
    __syncthreads();
  }

  #pragma unroll
  for (int j = 0; j < 4; ++j) {
    float m_ = accS[0][j];
    #pragma unroll
    for (int n = 1; n < 16; ++n) m_ = fmaxf(m_, accS[n][j]);
    #pragma unroll
    for (int msk = 1; msk < 16; msk <<= 1) m_ = fmaxf(m_, __shfl_xor(m_, msk));
    float s_ = 0.f;
    #pragma unroll
    for (int n = 0; n < 16; ++n) {
      float p = __expf(accS[n][j] - m_);
      accS[n][j] = p;
      s_ += p;
    }
    #pragma unroll
    for (int msk = 1; msk < 16; msk <<= 1) s_ += __shfl_xor(s_, msk);
    float ri = 1.f / s_;
    #pragma unroll
    for (int n = 0; n < 16; ++n) accS[n][j] *= ri;
  }

  // PV: Ps write -> __syncthreads() -> ldfrag is REQUIRED (round-6 NaN lesson)
  f32x4 accO[16];
  #pragma unroll
  for (int n = 0; n < 16; ++n) accO[n] = (f32x4){0.f,0.f,0.f,0.f};

  #pragma unroll
  for (int kt = 0; kt < 4; ++kt) {
    if (kt < 3) {
      const ushort* vp = vg + (kt + 1)*64;
      #pragma unroll
      for (int u = 0; u < 8; ++u) rv[u] = *(const uint4*)(vp + u*8);
    }
    #pragma unroll
    for (int ns = 0; ns < 4; ++ns)
      #pragma unroll
      for (int j = 0; j < 4; ++j)
        Ps[wid][(4*h + j)*68 + ns*16 + lr] = f2bf(accS[kt*4 + ns][j]);
    __syncthreads();
    #pragma unroll
    for (int ks = 0; ks < 2; ++ks) {
      s16x8 pf = ldfrag(&Ps[wid][lr*68 + ks*32 + h*8]);
      #pragma unroll
      for (int ns = 0; ns < 16; ++ns) {
        s16x8 vf = ldfrag(&KV[(ns*16 + lr)*68 + ks*32 + h*8]);
        accO[ns] = __builtin_amdgcn_mfma_f32_16x16x32_bf16(pf, vf, accO[ns], 0,0,0);
      }
    }
    __syncthreads();
    if (kt < 3) {
      #pragma unroll
      for (int u = 0; u < 8; ++u) st8(vd + u*8, rv[u]);
      __syncthreads();
    }
  }

  #pragma unroll
  for (int ns = 0; ns < 16; ++ns)
    #pragma unroll
    for (int j = 0; j < 4; ++j)
      KV[(wid*16 + 4*h + j)*260 + ns*16 + lr] = f2bf(accO[ns][j]);
  __syncthreads();
  ushort* aob = AO + (size_t)w*65536;
  #pragma unroll
  for (int it = 0; it < 8; ++it) {
    int task = tid + 256*it;
    int r = task >> 5, seg = task & 31;
    const ushort* sp = &KV[r*260 + seg*8];
    uint4 v;
    ((ull*)&v)[0] = *(const ull*)sp;
    ((ull*)&v)[1] = *(const ull*)(sp + 4);
    *(uint4*)(aob + (size_t)(q0 + r)*256 + seg*8) = v;
  }
}

// ---------------- output projection + residual: 128x128 blocks, 64x64/wave ----------------
__global__ __launch_bounds__(256, 3) void k_oproj(const float* __restrict__ x,
    const ushort* __restrict__ AO, const ushort* __restrict__ woE,
    const float* __restrict__ biasAll, float* __restrict__ y) {
  int g = blockIdx.x;
  int i = g >> 3;
  int w = (g & 7)*128 + (i >> 2);
  int q = i & 3;
  int o0 = (q >> 1)*128, t0 = (q & 1)*128;
  int b = w >> 8, wy = (w >> 4) & 15, wx = w & 15;
  int tid = threadIdx.x, l = tid & 63, wid = tid >> 6, h = l >> 4, lr = l & 15;
  int wr = wid >> 1, wc = wid & 1;

  __shared__ __align__(16) ushort smem[18432];

  const ushort* abase = AO + (size_t)w*65536 + (size_t)t0*256;
  const ushort* wbase = woE + (size_t)o0*256;

  int srow = tid >> 1, shh = (tid & 1)*16;
  const ushort* ag = abase + (size_t)srow*256 + shh;
  const ushort* wg = wbase + (size_t)srow*256 + shh;

  f32x4 acc[4][4];
  #pragma unroll
  for (int a = 0; a < 4; ++a)
    #pragma unroll
    for (int n = 0; n < 4; ++n) acc[a][n] = (f32x4){0.f,0.f,0.f,0.f};

  uint4 rw0, rw1, ra0, ra1;
  rw0 = *(const uint4*)(wg);     rw1 = *(const uint4*)(wg + 8);
  ra0 = *(const uint4*)(ag);     ra1 = *(const uint4*)(ag + 8);
  {
    ushort* wd = smem + srow*36 + shh;
    st8(wd, rw0); st8(wd + 8, rw1);
    ushort* ad = smem + 4608 + srow*36 + shh;
    st8(ad, ra0); st8(ad + 8, ra1);
  }
  __syncthreads();

  int cur = 0;
  for (int ck = 0; ck < 8; ++ck) {
    if (ck < 7) {
      const ushort* wp = wg + (ck + 1)*32;
      const ushort* ap = ag + (ck + 1)*32;
      rw0 = *(const uint4*)(wp);   rw1 = *(const uint4*)(wp + 8);
      ra0 = *(const uint4*)(ap);   ra1 = *(const uint4*)(ap + 8);
    }
    const ushort* wb = smem + cur*9216;
    const ushort* ab = smem + cur*9216 + 4608;
    s16x8 af[4], bf[4];
    #pragma unroll
    for (int ms = 0; ms < 4; ++ms)
      af[ms] = ldfrag(wb + (size_t)(wr*64 + ms*16 + lr)*36 + h*8);
    #pragma unroll
    for (int ns = 0; ns < 4; ++ns)
      bf[ns] = ldfrag(ab + (size_t)(wc*64 + ns*16 + lr)*36 + h*8);
    #pragma unroll
    for (int ms = 0; ms < 4; ++ms)
      #pragma unroll
      for (int ns = 0; ns < 4; ++ns)
        acc[ms][ns] = __builtin_amdgcn_mfma_f32_16x16x32_bf16(af[ms], bf[ns], acc[ms][ns], 0,0,0);
    if (ck < 7) {
      ushort* wd = smem + (cur^1)*9216 + srow*36 + shh;
      st8(wd, rw0); st8(wd + 8, rw1);
      ushort* ad = smem + (cur^1)*9216 + 4608 + srow*36 + shh;
      st8(ad, ra0); st8(ad + 8, ra1);
    }
    __syncthreads();
    cur ^= 1;
  }

  const float* xw = x + (size_t)b*IMG_ + wy*16*256 + wx*16;
  float* yw = y + (size_t)b*IMG_ + wy*16*256 + wx*16;
  #pragma unroll
  for (int ms = 0; ms < 4; ++ms) {
    f32x4 b4 = *(const f32x4*)&biasAll[768 + o0 + wr*64 + ms*16 + 4*h];
    #pragma unroll
    for (int j = 0; j < 4; ++j) {
      int o = o0 + wr*64 + ms*16 + 4*h + j;
      #pragma unroll
      for (int ns = 0; ns < 4; ++ns) {
        int t = t0 + wc*64 + ns*16 + lr;
        size_t off = (size_t)o*HW_ + (t >> 4)*256 + (t & 15);
        yw[off] = xw[off] + acc[ms][ns][j] + b4[j];
      }
    }
  }
}

extern "C" void kernel_launch(void* const* d_in, const int* in_sizes, int n_in,
                              void* d_out, int out_size, void* d_ws, size_t ws_size,
                              hipStream_t stream) {
  const float* x     = (const float*)d_in[0];
  const float* gamma = (const float*)d_in[1];
  const float* beta  = (const float*)d_in[2];
  const float* wq = (const float*)d_in[3];
  const float* bq = (const float*)d_in[4];
  const float* wk = (const float*)d_in[5];
  const float* bk = (const float*)d_in[6];
  const float* wv = (const float*)d_in[7];
  const float* bv = (const float*)d_in[8];
  const float* wo = (const float*)d_in[9];
  const float* bo = (const float*)d_in[10];
  float* y = (float*)d_out;
  char* ws = (char*)d_ws;

  float2* part    = (float2*)ws;                        // 8 KB
  float*  biasAll = (float*)(ws + 8192);                // 4 KB
  float2* stats   = (float2*)(ws + 16384);              // 1 KB
  ushort* wAll    = (ushort*)(ws + 32768);              // 384 KB
  ushort* woE     = (ushort*)(ws + 32768 + 393216);     // 128 KB
  ushort* Qt      = (ushort*)(ws + 2097152);            // 134 MB (also AO)
  // d_out holds Kt @0 and V @+134MB until k_oproj overwrites all of it with y.
  ushort* Kt = (ushort*)d_out;
  ushort* V  = (ushort*)d_out + (size_t)67108864;

  k_stats1<<<1024, 256, 0, stream>>>(x, part);
  k_stats2<<<1, 128, 0, stream>>>(part, stats);
  k_fold<<<4, 256, 0, stream>>>(wq,bq,wk,bk,wv,bv,wo,bo,gamma,beta,wAll,woE,biasAll);
  k_proj<<<12288, 256, 0, stream>>>(x, stats, wAll, biasAll, Qt, Kt, V);
  k_attn<<<4096, 256, 0, stream>>>(Qt, Kt, V, Qt /*AO alias: disjoint rows*/);
  k_oproj<<<4096, 256, 0, stream>>>(x, Qt /*AO*/, woE, biasAll, y);
}

// Round 11
// 918.864 us; speedup vs baseline: 1.0190x; 1.0076x over previous
//
#include <hip/hip_runtime.h>

#define C_ 256
#define HW_ 65536
#define IMG_ (C_*HW_)

typedef __attribute__((ext_vector_type(4))) float f32x4;
typedef __attribute__((ext_vector_type(8))) short s16x8;
typedef unsigned long long ull;

__device__ __forceinline__ ushort f2bf(float f) {
  union { float f; unsigned u; } v; v.f = f;
  unsigned u = v.u;
  return (ushort)((u + 0x7fffu + ((u >> 16) & 1u)) >> 16);
}

// packed f32x2 -> bf16x2 (RNE), gfx950 HW op; no builtin exists (T12 recipe)
__device__ __forceinline__ unsigned cvtpk(float lo, float hi) {
  unsigned r;
  asm("v_cvt_pk_bf16_f32 %0, %1, %2" : "=v"(r) : "v"(lo), "v"(hi));
  return r;
}

__device__ __forceinline__ s16x8 ldfrag(const ushort* p) {
  s16x8 v;
  ((ull*)&v)[0] = *(const ull*)(p);
  ((ull*)&v)[1] = *(const ull*)(p + 4);
  return v;
}

__device__ __forceinline__ void st8(ushort* d, uint4 u) {
  *(ull*)(d)     = ((ull*)&u)[0];
  *(ull*)(d + 4) = ((ull*)&u)[1];
}

// ---------------- per-plane stats ----------------
__global__ void k_stats1(const float* __restrict__ x, float2* __restrict__ part) {
  int bid = blockIdx.x;                  // 1024 = (b,c) planes
  int tid = threadIdx.x;
  const f32x4* p = (const f32x4*)(x + (size_t)bid*65536);
  float s = 0.f, ss = 0.f;
  #pragma unroll 4
  for (int i = tid; i < 16384; i += 256) {
    f32x4 v = p[i];
    s  += v[0]+v[1]+v[2]+v[3];
    ss += v[0]*v[0]+v[1]*v[1]+v[2]*v[2]+v[3]*v[3];
  }
  __shared__ float sa[256], sb[256];
  sa[tid]=s; sb[tid]=ss; __syncthreads();
  for (int k=128;k>0;k>>=1){
    if (tid<k){ sa[tid]+=sa[tid+k]; sb[tid]+=sb[tid+k]; }
    __syncthreads();
  }
  if (tid==0) part[bid] = make_float2(sa[0], sb[0]);
}

// ---------------- reduce to per-(b,group) mean/rstd ----------------
__global__ void k_stats2(const float2* __restrict__ part, float2* __restrict__ stats) {
  int i = threadIdx.x;              // 128 = b*32 + g
  int b = i >> 5, gg = i & 31;
  float s = 0.f, ss = 0.f;
  for (int j = 0; j < 8; ++j) { float2 v = part[b*256 + gg*8 + j]; s += v.x; ss += v.y; }
  float mean = s * (1.f/524288.f);
  float var  = ss * (1.f/524288.f) - mean*mean;
  stats[i] = make_float2(mean, rsqrtf(var + 1e-6f));
}

// ---------------- fold full GN (per-batch rstd/mean + gamma/beta) into bf16 weights ----------------
// id 0..11: m = id>>2 (Q/K/V), b = id&3: W'[o][ci] = W*gamma*rstd*s; bias' = (b + W·(beta-mean*rstd*gamma))*s
// id 12: wo plain convert
__global__ void k_fold(const float* __restrict__ wq, const float* __restrict__ bq,
                       const float* __restrict__ wk, const float* __restrict__ bk,
                       const float* __restrict__ wv, const float* __restrict__ bv,
                       const float* __restrict__ wo, const float* __restrict__ bo,
                       const float* __restrict__ gamma, const float* __restrict__ beta,
                       const float2* __restrict__ stats,
                       ushort* __restrict__ wAll, ushort* __restrict__ woE,
                       float* __restrict__ biasAll) {
  int id = blockIdx.x, o = threadIdx.x;
  if (id == 12) {
    for (int c4 = 0; c4 < 64; ++c4) {
      ushort4 pk;
      pk.x = f2bf(wo[o*256 + c4*4 + 0]);
      pk.y = f2bf(wo[o*256 + c4*4 + 1]);
      pk.z = f2bf(wo[o*256 + c4*4 + 2]);
      pk.w = f2bf(wo[o*256 + c4*4 + 3]);
      *(ushort4*)&woE[o*256 + c4*4] = pk;
    }
    biasAll[3072 + o] = bo[o];
    return;
  }
  int m = id >> 2, b = id & 3;
  __shared__ float aS[256], cS[256];
  {
    float2 st = stats[b*32 + (o >> 3)];
    float a = gamma[o] * st.y;
    aS[o] = a;
    cS[o] = beta[o] - st.x * a;
  }
  __syncthreads();
  const float* W  = m==0 ? wq : m==1 ? wk : wv;
  const float* bi = m==0 ? bq : m==1 ? bk : bv;
  float s = (m==0) ? 0.0625f : 1.0f;
  float acc = bi[o];
  ushort* dst = wAll + ((size_t)(m*4 + b)*256 + o)*256;
  for (int c4 = 0; c4 < 64; ++c4) {
    ushort4 pk; float wv_;
    wv_ = W[o*256 + c4*4 + 0]; acc += wv_*cS[c4*4+0]; pk.x = f2bf(wv_*aS[c4*4+0]*s);
    wv_ = W[o*256 + c4*4 + 1]; acc += wv_*cS[c4*4+1]; pk.y = f2bf(wv_*aS[c4*4+1]*s);
    wv_ = W[o*256 + c4*4 + 2]; acc += wv_*cS[c4*4+2]; pk.z = f2bf(wv_*aS[c4*4+2]*s);
    wv_ = W[o*256 + c4*4 + 3]; acc += wv_*cS[c4*4+3]; pk.w = f2bf(wv_*aS[c4*4+3]*s);
    *(ushort4*)&dst[c4*4] = pk;
  }
  biasAll[(m*4 + b)*256 + o] = acc * s;
}

// ---------------- fused QKV projection (GN pre-folded per batch): 128x128, 64x64/wave ----------------
// mat 0/1 -> Qt/Kt[win][t][c]; mat 2 -> V[win][c][t]. 12 blocks/window, XCD-chunked.
// X staging: thread = tq(0..31)*8 + cq(0..7) -> 4 ci x 4 t; 4x16B coalesced loads (16 full
// lines/wave), 8 cvt_pk, 4 ds_write_b64 transposed. No per-element GN math (folded into W).
__global__ __launch_bounds__(256, 3) void k_proj(const float* __restrict__ x,
    const ushort* __restrict__ wAll, const float* __restrict__ biasAll,
    ushort* __restrict__ Qt, ushort* __restrict__ Kt, ushort* __restrict__ V) {
  int g = blockIdx.x;
  int xcd = g & 7, i = g >> 3;
  int wq_ = i / 12; int win = xcd*128 + wq_; int r = i - wq_*12;
  int mat = r >> 2, q = r & 3;
  int t0 = (q >> 1)*128, c0 = (q & 1)*128;
  int b = win >> 8, wy = (win >> 4) & 15, wx = win & 15;
  int tid = threadIdx.x, l = tid & 63, wid = tid >> 6, h = l >> 4, lr = l & 15;
  int wr = wid >> 1, wc = wid & 1;

  // dbuf: buffer k at k*9216 (ushort units): X[128t][36] @+0, W[128co][36] @+4608
  __shared__ __align__(16) ushort smem[18432];

  const float* xw = x + (size_t)b*IMG_ + (size_t)wy*16*256 + wx*16;
  const ushort* wsrc = wAll + (size_t)(mat*4 + b)*65536 + (size_t)c0*256;

  // X staging geometry
  int cq = tid & 7, tq = tid >> 3;
  int t_abs = t0 + 4*tq;
  const float* xg = xw + (size_t)(4*cq)*HW_ + (t_abs >> 4)*256 + (t_abs & 15);
  ushort* xdl = smem + (size_t)(4*tq)*36 + 4*cq;

  // W staging: 2 threads/row, 32B each
  int srow = tid >> 1, shh = (tid & 1)*16;
  const ushort* wg = wsrc + (size_t)srow*256 + shh;

  f32x4 acc[4][4];
  #pragma unroll
  for (int a = 0; a < 4; ++a)
    #pragma unroll
    for (int n = 0; n < 4; ++n) acc[a][n] = (f32x4){0.f,0.f,0.f,0.f};

  int aoff = (mat < 2) ? 0 : 4608;     // A rows: t (X) for Q/K, co (W) for V
  int boff = (mat < 2) ? 4608 : 0;

  f32x4 ld0, ld1, ld2, ld3;
  uint4 rw0, rw1;
  // prologue: load ck=0
  ld0 = *(const f32x4*)(xg);
  ld1 = *(const f32x4*)(xg + HW_);
  ld2 = *(const f32x4*)(xg + 2*HW_);
  ld3 = *(const f32x4*)(xg + 3*HW_);
  rw0 = *(const uint4*)(wg);       rw1 = *(const uint4*)(wg + 8);
  {
    #pragma unroll
    for (int k = 0; k < 4; ++k) {
      ull wv = (ull)cvtpk(ld0[k], ld1[k]) | ((ull)cvtpk(ld2[k], ld3[k]) << 32);
      *(ull*)&xdl[k*36] = wv;
    }
    ushort* wd = smem + 4608 + srow*36 + shh;
    st8(wd, rw0); st8(wd + 8, rw1);
  }
  __syncthreads();

  int cur = 0;
  for (int ck = 0; ck < 8; ++ck) {
    if (ck < 7) {
      const float* xp = xg + (size_t)(ck + 1)*32*HW_;
      ld0 = *(const f32x4*)(xp);
      ld1 = *(const f32x4*)(xp + HW_);
      ld2 = *(const f32x4*)(xp + 2*HW_);
      ld3 = *(const f32x4*)(xp + 3*HW_);
      const ushort* wp = wg + (ck + 1)*32;
      rw0 = *(const uint4*)(wp);      rw1 = *(const uint4*)(wp + 8);
    }
    const ushort* ab = smem + cur*9216 + aoff;
    const ushort* bb = smem + cur*9216 + boff;
    s16x8 af[4], bf[4];
    #pragma unroll
    for (int ms = 0; ms < 4; ++ms)
      af[ms] = ldfrag(ab + (size_t)(wr*64 + ms*16 + lr)*36 + h*8);
    #pragma unroll
    for (int ns = 0; ns < 4; ++ns)
      bf[ns] = ldfrag(bb + (size_t)(wc*64 + ns*16 + lr)*36 + h*8);
    #pragma unroll
    for (int ms = 0; ms < 4; ++ms)
      #pragma unroll
      for (int ns = 0; ns < 4; ++ns)
        acc[ms][ns] = __builtin_amdgcn_mfma_f32_16x16x32_bf16(af[ms], bf[ns], acc[ms][ns], 0,0,0);
    if (ck < 7) {
      ushort* xd = xdl + (cur^1)*9216;
      #pragma unroll
      for (int k = 0; k < 4; ++k) {
        ull wv = (ull)cvtpk(ld0[k], ld1[k]) | ((ull)cvtpk(ld2[k], ld3[k]) << 32);
        *(ull*)&xd[k*36] = wv;
      }
      ushort* wd = smem + (cur^1)*9216 + 4608 + srow*36 + shh;
      st8(wd, rw0); st8(wd + 8, rw1);
    }
    __syncthreads();
    cur ^= 1;
  }

  // ---- epilogue: 2 slab passes [128][68] over B-dim 64-halves; wide 16B stores ----
  ushort* dst = (mat == 0) ? Qt + (size_t)win*65536
              : (mat == 1) ? Kt + (size_t)win*65536
                           : V  + (size_t)win*65536;
  int row0 = (mat < 2) ? t0 : c0;
  int col0 = (mat < 2) ? c0 : t0;

  float bc[4]; f32x4 br[4];
  if (mat < 2) {
    #pragma unroll
    for (int ns = 0; ns < 4; ++ns)
      bc[ns] = biasAll[(mat*4 + b)*256 + c0 + wc*64 + ns*16 + lr];
  } else {
    #pragma unroll
    for (int ms = 0; ms < 4; ++ms)
      br[ms] = *(const f32x4*)&biasAll[(2*4 + b)*256 + c0 + wr*64 + ms*16 + 4*h];
  }

  #pragma unroll
  for (int sl = 0; sl < 2; ++sl) {
    if (wc == sl) {
      #pragma unroll
      for (int ms = 0; ms < 4; ++ms)
        #pragma unroll
        for (int ns = 0; ns < 4; ++ns)
          #pragma unroll
          for (int j = 0; j < 4; ++j) {
            int row = wr*64 + ms*16 + 4*h + j;
            float v = acc[ms][ns][j] + ((mat < 2) ? bc[ns] : br[ms][j]);
            smem[row*68 + ns*16 + lr] = f2bf(v);
          }
    }
    __syncthreads();
    #pragma unroll
    for (int p = 0; p < 4; ++p) {
      int rr = p*32 + (tid >> 3), seg = tid & 7;
      const ushort* sp = &smem[rr*68 + seg*8];
      uint4 v;
      ((ull*)&v)[0] = *(const ull*)sp;
      ((ull*)&v)[1] = *(const ull*)(sp + 4);
      *(uint4*)(dst + (size_t)(row0 + rr)*256 + col0 + sl*64 + seg*8) = v;
    }
    if (sl == 0) __syncthreads();
  }
}

// ---------------- windowed attention: q-split waves, Q-in-regs, 64-key tiles ----------------
__global__ __launch_bounds__(256, 2) void k_attn(const ushort* __restrict__ Qt,
    const ushort* __restrict__ Kt, const ushort* __restrict__ V,
    ushort* __restrict__ AO) {
  int g = blockIdx.x;
  int i = g >> 3;
  int w = (g & 7)*128 + (i >> 2), qt = i & 3;
  int q0 = qt * 64;
  int tid = threadIdx.x, l = tid & 63, wid = tid >> 6, h = l >> 4, lr = l & 15;
  __shared__ __align__(16) ushort KV[17408];
  __shared__ __align__(16) ushort Ps[4][1088];   // per-wave P-subtile [16 q][68]
  const ushort* qbase = Qt + (size_t)w*65536;
  const ushort* kbase = Kt + (size_t)w*65536;
  const ushort* vbase = V  + (size_t)w*65536;

  s16x8 qf[8];
  {
    const ushort* qp = qbase + (size_t)(q0 + wid*16 + lr)*256 + h*8;
    #pragma unroll
    for (int dk = 0; dk < 8; ++dk) {
      uint4 u = *(const uint4*)(qp + dk*32);
      qf[dk] = *(s16x8*)&u;
    }
  }

  int krow = tid >> 2, kseg = (tid & 3)*64;
  const ushort* kg = kbase + (size_t)krow*256 + kseg;
  ushort* kd = &KV[krow*260 + kseg];
  const ushort* vg = vbase + (size_t)tid*256;
  ushort* vd = &KV[tid*68];

  uint4 rv[8];
  #pragma unroll
  for (int u = 0; u < 8; ++u) rv[u] = *(const uint4*)(kg + u*8);
  #pragma unroll
  for (int u = 0; u < 8; ++u) st8(kd + u*8, rv[u]);
  __syncthreads();

  f32x4 accS[16];
  #pragma unroll
  for (int n = 0; n < 16; ++n) accS[n] = (f32x4){0.f,0.f,0.f,0.f};

  #pragma unroll
  for (int kt = 0; kt < 4; ++kt) {
    if (kt < 3) {
      const ushort* kp = kg + (size_t)(kt + 1)*64*256;
      #pragma unroll
      for (int u = 0; u < 8; ++u) rv[u] = *(const uint4*)(kp + u*8);
    } else {
      #pragma unroll
      for (int u = 0; u < 8; ++u) rv[u] = *(const uint4*)(vg + u*8);
    }
    #pragma unroll
    for (int ns = 0; ns < 4; ++ns) {
      #pragma unroll
      for (int dstep = 0; dstep < 8; ++dstep) {
        s16x8 kf = ldfrag(&KV[(ns*16 + lr)*260 + dstep*32 + h*8]);
        accS[kt*4 + ns] = __builtin_amdgcn_mfma_f32_16x16x32_bf16(qf[dstep], kf, accS[kt*4 + ns], 0,0,0);
      }
    }
    __syncthreads();
    if (kt < 3) {
      #pragma unroll
      for (int u = 0; u < 8; ++u) st8(kd + u*8, rv[u]);
    } else {
      #pragma unroll
      for (int u = 0; u < 8; ++u) st8(vd + u*8, rv[u]);
    }
    __syncthreads();
  }

  #pragma unroll
  for (int j = 0; j < 4; ++j) {
    float m_ = accS[0][j];
    #pragma unroll
    for (int n = 1; n < 16; ++n) m_ = fmaxf(m_, accS[n][j]);
    #pragma unroll
    for (int msk = 1; msk < 16; msk <<= 1) m_ = fmaxf(m_, __shfl_xor(m_, msk));
    float s_ = 0.f;
    #pragma unroll
    for (int n = 0; n < 16; ++n) {
      float p = __expf(accS[n][j] - m_);
      accS[n][j] = p;
      s_ += p;
    }
    #pragma unroll
    for (int msk = 1; msk < 16; msk <<= 1) s_ += __shfl_xor(s_, msk);
    float ri = 1.f / s_;
    #pragma unroll
    for (int n = 0; n < 16; ++n) accS[n][j] *= ri;
  }

  // PV: Ps write -> __syncthreads() -> ldfrag is REQUIRED (round-6 NaN lesson)
  f32x4 accO[16];
  #pragma unroll
  for (int n = 0; n < 16; ++n) accO[n] = (f32x4){0.f,0.f,0.f,0.f};

  #pragma unroll
  for (int kt = 0; kt < 4; ++kt) {
    if (kt < 3) {
      const ushort* vp = vg + (kt + 1)*64;
      #pragma unroll
      for (int u = 0; u < 8; ++u) rv[u] = *(const uint4*)(vp + u*8);
    }
    #pragma unroll
    for (int ns = 0; ns < 4; ++ns)
      #pragma unroll
      for (int j = 0; j < 4; ++j)
        Ps[wid][(4*h + j)*68 + ns*16 + lr] = f2bf(accS[kt*4 + ns][j]);
    __syncthreads();
    #pragma unroll
    for (int ks = 0; ks < 2; ++ks) {
      s16x8 pf = ldfrag(&Ps[wid][lr*68 + ks*32 + h*8]);
      #pragma unroll
      for (int ns = 0; ns < 16; ++ns) {
        s16x8 vf = ldfrag(&KV[(ns*16 + lr)*68 + ks*32 + h*8]);
        accO[ns] = __builtin_amdgcn_mfma_f32_16x16x32_bf16(pf, vf, accO[ns], 0,0,0);
      }
    }
    __syncthreads();
    if (kt < 3) {
      #pragma unroll
      for (int u = 0; u < 8; ++u) st8(vd + u*8, rv[u]);
      __syncthreads();
    }
  }

  #pragma unroll
  for (int ns = 0; ns < 16; ++ns)
    #pragma unroll
    for (int j = 0; j < 4; ++j)
      KV[(wid*16 + 4*h + j)*260 + ns*16 + lr] = f2bf(accO[ns][j]);
  __syncthreads();
  ushort* aob = AO + (size_t)w*65536;
  #pragma unroll
  for (int it = 0; it < 8; ++it) {
    int task = tid + 256*it;
    int r = task >> 5, seg = task & 31;
    const ushort* sp = &KV[r*260 + seg*8];
    uint4 v;
    ((ull*)&v)[0] = *(const ull*)sp;
    ((ull*)&v)[1] = *(const ull*)(sp + 4);
    *(uint4*)(aob + (size_t)(q0 + r)*256 + seg*8) = v;
  }
}

// ---------------- output projection + residual: 128x128 blocks, 64x64/wave ----------------
__global__ __launch_bounds__(256, 3) void k_oproj(const float* __restrict__ x,
    const ushort* __restrict__ AO, const ushort* __restrict__ woE,
    const float* __restrict__ biasAll, float* __restrict__ y) {
  int g = blockIdx.x;
  int i = g >> 3;
  int w = (g & 7)*128 + (i >> 2);
  int q = i & 3;
  int o0 = (q >> 1)*128, t0 = (q & 1)*128;
  int b = w >> 8, wy = (w >> 4) & 15, wx = w & 15;
  int tid = threadIdx.x, l = tid & 63, wid = tid >> 6, h = l >> 4, lr = l & 15;
  int wr = wid >> 1, wc = wid & 1;

  __shared__ __align__(16) ushort smem[18432];

  const ushort* abase = AO + (size_t)w*65536 + (size_t)t0*256;
  const ushort* wbase = woE + (size_t)o0*256;

  int srow = tid >> 1, shh = (tid & 1)*16;
  const ushort* ag = abase + (size_t)srow*256 + shh;
  const ushort* wg = wbase + (size_t)srow*256 + shh;

  f32x4 acc[4][4];
  #pragma unroll
  for (int a = 0; a < 4; ++a)
    #pragma unroll
    for (int n = 0; n < 4; ++n) acc[a][n] = (f32x4){0.f,0.f,0.f,0.f};

  uint4 rw0, rw1, ra0, ra1;
  rw0 = *(const uint4*)(wg);     rw1 = *(const uint4*)(wg + 8);
  ra0 = *(const uint4*)(ag);     ra1 = *(const uint4*)(ag + 8);
  {
    ushort* wd = smem + srow*36 + shh;
    st8(wd, rw0); st8(wd + 8, rw1);
    ushort* ad = smem + 4608 + srow*36 + shh;
    st8(ad, ra0); st8(ad + 8, ra1);
  }
  __syncthreads();

  int cur = 0;
  for (int ck = 0; ck < 8; ++ck) {
    if (ck < 7) {
      const ushort* wp = wg + (ck + 1)*32;
      const ushort* ap = ag + (ck + 1)*32;
      rw0 = *(const uint4*)(wp);   rw1 = *(const uint4*)(wp + 8);
      ra0 = *(const uint4*)(ap);   ra1 = *(const uint4*)(ap + 8);
    }
    const ushort* wb = smem + cur*9216;
    const ushort* ab = smem + cur*9216 + 4608;
    s16x8 af[4], bf[4];
    #pragma unroll
    for (int ms = 0; ms < 4; ++ms)
      af[ms] = ldfrag(wb + (size_t)(wr*64 + ms*16 + lr)*36 + h*8);
    #pragma unroll
    for (int ns = 0; ns < 4; ++ns)
      bf[ns] = ldfrag(ab + (size_t)(wc*64 + ns*16 + lr)*36 + h*8);
    #pragma unroll
    for (int ms = 0; ms < 4; ++ms)
      #pragma unroll
      for (int ns = 0; ns < 4; ++ns)
        acc[ms][ns] = __builtin_amdgcn_mfma_f32_16x16x32_bf16(af[ms], bf[ns], acc[ms][ns], 0,0,0);
    if (ck < 7) {
      ushort* wd = smem + (cur^1)*9216 + srow*36 + shh;
      st8(wd, rw0); st8(wd + 8, rw1);
      ushort* ad = smem + (cur^1)*9216 + 4608 + srow*36 + shh;
      st8(ad, ra0); st8(ad + 8, ra1);
    }
    __syncthreads();
    cur ^= 1;
  }

  const float* xw = x + (size_t)b*IMG_ + wy*16*256 + wx*16;
  float* yw = y + (size_t)b*IMG_ + wy*16*256 + wx*16;
  #pragma unroll
  for (int ms = 0; ms < 4; ++ms) {
    f32x4 b4 = *(const f32x4*)&biasAll[3072 + o0 + wr*64 + ms*16 + 4*h];
    #pragma unroll
    for (int j = 0; j < 4; ++j) {
      int o = o0 + wr*64 + ms*16 + 4*h + j;
      #pragma unroll
      for (int ns = 0; ns < 4; ++ns) {
        int t = t0 + wc*64 + ns*16 + lr;
        size_t off = (size_t)o*HW_ + (t >> 4)*256 + (t & 15);
        yw[off] = xw[off] + acc[ms][ns][j] + b4[j];
      }
    }
  }
}

extern "C" void kernel_launch(void* const* d_in, const int* in_sizes, int n_in,
                              void* d_out, int out_size, void* d_ws, size_t ws_size,
                              hipStream_t stream) {
  const float* x     = (const float*)d_in[0];
  const float* gamma = (const float*)d_in[1];
  const float* beta  = (const float*)d_in[2];
  const float* wq = (const float*)d_in[3];
  const float* bq = (const float*)d_in[4];
  const float* wk = (const float*)d_in[5];
  const float* bk = (const float*)d_in[6];
  const float* wv = (const float*)d_in[7];
  const float* bv = (const float*)d_in[8];
  const float* wo = (const float*)d_in[9];
  const float* bo = (const float*)d_in[10];
  float* y = (float*)d_out;
  char* ws = (char*)d_ws;

  float2* part    = (float2*)ws;                        // 8 KB
  float*  biasAll = (float*)(ws + 8192);                // 13.3 KB (3*4*256 + 256 floats)
  float2* stats   = (float2*)(ws + 24576);              // 1 KB
  ushort* wAll    = (ushort*)(ws + 32768);              // 1.5 MB (per-batch folded QKV)
  ushort* woE     = (ushort*)(ws + 32768 + 1572864);    // 128 KB
  ushort* Qt      = (ushort*)(ws + 2097152);            // 134 MB (also AO)
  // d_out holds Kt @0 and V @+134MB until k_oproj overwrites all of it with y.
  ushort* Kt = (ushort*)d_out;
  ushort* V  = (ushort*)d_out + (size_t)67108864;

  k_stats1<<<1024, 256, 0, stream>>>(x, part);
  k_stats2<<<1, 128, 0, stream>>>(part, stats);
  k_fold<<<13, 256, 0, stream>>>(wq,bq,wk,bk,wv,bv,wo,bo,gamma,beta,stats,wAll,woE,biasAll);
  k_proj<<<12288, 256, 0, stream>>>(x, wAll, biasAll, Qt, Kt, V);
  k_attn<<<4096, 256, 0, stream>>>(Qt, Kt, V, Qt /*AO alias: disjoint rows*/);
  k_oproj<<<4096, 256, 0, stream>>>(x, Qt /*AO*/, woE, biasAll, y);
}